// Round 1
// 198.197 us; speedup vs baseline: 1.0767x; 1.0767x over previous
//
#include <hip/hip_runtime.h>

// BlockRelLinear round 5: fused single-kernel.
// out[p, n*8+o] = sum_i x[p, n*8+i] * w[rel[p], n, i, o]
//
// Rounds 1-4 used relation-sort (hist/scan/scatter + gather main): k_main was
// 72us but the pre-passes + 5 launches burned ~140us of the 213us total, all
// to keep a 512KB weight table in registers. Round 5 drops the sort entirely:
//  - 4 "quads" of 4 output-blocks; a block's quad weight slice = 128KB in LDS.
//  - grid 256 x 1024 thr (1 block/CU, 16 waves/CU). Thread = (point, n).
//  - x/out accessed as full 128B lines, each line touched by exactly one wave
//    (p*512 + q*128 is line-aligned): perfect read+write efficiency, no gather.
//  - LDS weight reads indexed by random rel[p] are XOR-swizzled in 16B chunks
//    by (r&15) so the 64 lanes spread across all banks (T2-style).
//  - depth-1 prefetch of (rel, x) per thread; no atomics, no workspace.
// HBM floor: 102MB x + 100MB out + 3.2MB rel ~= 33us @ 6.3TB/s.

__global__ __launch_bounds__(1024) void k_fused(
    const float* __restrict__ x, const float* __restrict__ w,
    const int* __restrict__ rel, float* __restrict__ out, int npoints)
{
    // [nl][r][chunk]: logical chunk c = i*2 + o/4 stored at position c ^ (r&15)
    __shared__ float4 wlds[4][128][16];          // 128 KB

    const int q = blockIdx.x >> 6;               // quad 0..3
    const int b = blockIdx.x & 63;               // 64 blocks per quad

    // ---- stage quad weights (coalesced: one wave-instr = one r's 1KB run) ----
    const float4* wsrc = reinterpret_cast<const float4*>(w);
    #pragma unroll
    for (int j = 0; j < 8; ++j) {
        int f  = threadIdx.x + j * 1024;         // 0..8191 = (r, nl, k)
        int r  = f >> 6;
        int lo = f & 63;                         // nl*16 + k
        int nl = lo >> 4;
        int k  = f & 15;
        wlds[nl][r][k ^ (r & 15)] = wsrc[r * 256 + q * 64 + lo];
    }
    __syncthreads();

    const int nl = threadIdx.x & 3;
    const int pt = threadIdx.x >> 2;             // 0..255
    const int chunk = (npoints + 63) >> 6;       // points per block (64 blocks/quad)
    const int plo = b * chunk;
    const int phi = min(plo + chunk, npoints);
    const int n  = q * 4 + nl;

    int p = plo + pt;
    if (p >= phi) return;                        // safe: no further __syncthreads

    const float* xb = x + n * 8;
    float*       ob = out + n * 8;

    // prologue loads
    int r = rel[p];
    const float4* xv = reinterpret_cast<const float4*>(xb + (size_t)p * 128);
    float4 x0 = xv[0], x1 = xv[1];

    while (true) {
        // ---- depth-1 prefetch (clamped so no divergence / OOB) ----
        int pn = p + 256;
        int pc = pn < phi ? pn : (phi - 1);
        int rn = rel[pc];
        const float4* xnv = reinterpret_cast<const float4*>(xb + (size_t)pc * 128);
        float4 xn0 = xnv[0], xn1 = xnv[1];

        // ---- compute current point ----
        const int s = r & 15;
        const float4* wr = wlds[nl][r];
        float xf[8] = {x0.x, x0.y, x0.z, x0.w, x1.x, x1.y, x1.z, x1.w};
        float a0 = 0.f, a1 = 0.f, a2 = 0.f, a3 = 0.f;
        float a4 = 0.f, a5 = 0.f, a6 = 0.f, a7 = 0.f;
        #pragma unroll
        for (int i = 0; i < 8; ++i) {            // same i-order as rounds 2-4 (absmax 0.0)
            float4 wA = wr[(2 * i)     ^ s];     // w[r][n][i][0..4)
            float4 wB = wr[(2 * i + 1) ^ s];     // w[r][n][i][4..8)
            float xi = xf[i];
            a0 = fmaf(xi, wA.x, a0);
            a1 = fmaf(xi, wA.y, a1);
            a2 = fmaf(xi, wA.z, a2);
            a3 = fmaf(xi, wA.w, a3);
            a4 = fmaf(xi, wB.x, a4);
            a5 = fmaf(xi, wB.y, a5);
            a6 = fmaf(xi, wB.z, a6);
            a7 = fmaf(xi, wB.w, a7);
        }
        float4* ov = reinterpret_cast<float4*>(ob + (size_t)p * 128);
        ov[0] = make_float4(a0, a1, a2, a3);
        ov[1] = make_float4(a4, a5, a6, a7);

        if (pn >= phi) break;
        p = pn; r = rn; x0 = xn0; x1 = xn1;
    }
}

// ---------- fallback (round-2 kernel) for unexpected shapes ----------
__global__ __launch_bounds__(256) void brl_kernel(
    const float* __restrict__ x, const float* __restrict__ w,
    const int* __restrict__ rel, float* __restrict__ out, int npoints)
{
    int tid = blockIdx.x * 256 + threadIdx.x;
    int p = tid >> 4;
    if (p >= npoints) return;
    int n = tid & 15;
    int r = rel[p];
    const float4* xv = reinterpret_cast<const float4*>(x + (size_t)p * 128 + n * 8);
    float4 x0 = xv[0], x1 = xv[1];
    float xf[8] = {x0.x, x0.y, x0.z, x0.w, x1.x, x1.y, x1.z, x1.w};
    const float4* wv = reinterpret_cast<const float4*>(w + ((size_t)r * 16 + n) * 64);
    float acc[8] = {0.f, 0.f, 0.f, 0.f, 0.f, 0.f, 0.f, 0.f};
    #pragma unroll
    for (int i = 0; i < 8; ++i) {
        float4 w0 = wv[2 * i], w1 = wv[2 * i + 1];
        float wf[8] = {w0.x, w0.y, w0.z, w0.w, w1.x, w1.y, w1.z, w1.w};
        #pragma unroll
        for (int o = 0; o < 8; ++o) acc[o] = fmaf(xf[i], wf[o], acc[o]);
    }
    float4* ov = reinterpret_cast<float4*>(out + (size_t)p * 128 + n * 8);
    ov[0] = make_float4(acc[0], acc[1], acc[2], acc[3]);
    ov[1] = make_float4(acc[4], acc[5], acc[6], acc[7]);
}

extern "C" void kernel_launch(void* const* d_in, const int* in_sizes, int n_in,
                              void* d_out, int out_size, void* d_ws, size_t ws_size,
                              hipStream_t stream) {
    const float* x   = (const float*)d_in[0];
    const float* w   = (const float*)d_in[1];
    const int*   rel = (const int*)d_in[2];
    float*       out = (float*)d_out;

    int npoints = in_sizes[2];
    int R = in_sizes[1] / 1024;          // R * nb(16) * ib(8) * ob(8)

    if (R == 128 && in_sizes[0] == npoints * 128) {
        k_fused<<<256, 1024, 0, stream>>>(x, w, rel, out, npoints);
    } else {
        int total = npoints * 16;
        brl_kernel<<<(total + 255) / 256, 256, 0, stream>>>(x, w, rel, out, npoints);
    }
}

// Round 2
// 197.315 us; speedup vs baseline: 1.0816x; 1.0045x over previous
//
#include <hip/hip_runtime.h>

// BlockRelLinear round 6: fused kernel, fixed LDS swizzle + depth-2 prefetch.
// out[p, n*8+o] = sum_i x[p, n*8+i] * w[rel[p], n, i, o]
//
// Round-5 post-mortem: SQ_LDS_BANK_CONFLICT=1.35e7 over ~200k ds_read_b128
// (~67 extra cyc/instr). Cause: swizzle pos = c ^ (r&15) inside wlds[nl][r][16]
// leaves nl at stride 2048 float4s == 0 mod 8 -> the 4 lanes of one point
// (same r, nl=0..3) always share a bank group with distinct addresses: forced
// 4-way conflict x random r collisions. Fix: row layout wlds[r][64] with
// logical chunk (nl,c) stored at pos = (c*4 + nl) ^ (r&63). Bank group =
// (4(c&1)|nl) ^ (r&7): same-point lanes hit 4 DISTINCT groups; r XOR-rotates
// points across groups. Expected ~9-10 cyc/instr vs 8-cyc floor (vs ~75 now).
// Also: depth-2 prefetch (3 reg buffers) to cover ~900cy HBM latency once the
// LDS critical path collapses. FMA order unchanged -> absmax 0.0.
// HBM floor: 102MB x + 100MB out + 3.2MB rel ~= 33us @ 6.3TB/s.

__global__ __launch_bounds__(1024) void k_fused(
    const float* __restrict__ x, const float* __restrict__ w,
    const int* __restrict__ rel, float* __restrict__ out, int npoints)
{
    // wlds[r][pos], pos = ((c<<2)|nl) ^ (r&63);  c = i*2 + o/4 (16 chunks), nl = n&3
    __shared__ float4 wlds[128][64];             // 128 KB

    const int q = blockIdx.x >> 6;               // quad 0..3 (n = q*4 + nl)
    const int b = blockIdx.x & 63;               // 64 blocks per quad

    // ---- stage quad weights, swizzled. Each wave writes one full permuted
    // 64-slot row per step -> conflict-free. ----
    const float4* wsrc = reinterpret_cast<const float4*>(w);
    #pragma unroll
    for (int j = 0; j < 8; ++j) {
        int f  = threadIdx.x + j * 1024;         // (r, nl, k)
        int r  = f >> 6;
        int lo = f & 63;                         // nl*16 + k
        int nl = lo >> 4;
        int k  = f & 15;
        wlds[r][((k << 2) | nl) ^ (r & 63)] = wsrc[r * 256 + q * 64 + lo];
    }
    __syncthreads();

    const int nl = threadIdx.x & 3;
    const int pt = threadIdx.x >> 2;             // 0..255
    const int chunk = (npoints + 63) >> 6;
    const int plo = b * chunk;
    const int phi = min(plo + chunk, npoints);
    const int n  = q * 4 + nl;

    int p1 = plo + pt;
    if (p1 >= phi) return;                       // no further __syncthreads

    const float* xb = x + n * 8;
    float*       ob = out + n * 8;

    // ---- pipeline prologue: slots 1 (next compute) and 2 in flight ----
    int r1 = rel[p1];
    const float4* xv1 = reinterpret_cast<const float4*>(xb + (size_t)p1 * 128);
    float4 xa1 = xv1[0], xb1 = xv1[1];

    int p2 = p1 + 256;                           // unclamped (control)
    int p2c = p2 < phi ? p2 : phi - 1;           // clamped (load)
    int r2 = rel[p2c];
    const float4* xv2 = reinterpret_cast<const float4*>(xb + (size_t)p2c * 128);
    float4 xa2 = xv2[0], xb2 = xv2[1];

    while (true) {
        // ---- depth-2 prefetch ----
        int p3 = p1 + 512;
        int p3c = p3 < phi ? p3 : phi - 1;
        int r3 = rel[p3c];
        const float4* xv3 = reinterpret_cast<const float4*>(xb + (size_t)p3c * 128);
        float4 xa3 = xv3[0], xb3 = xv3[1];

        // ---- compute current point p1 ----
        {
            const int s   = r1 & 63;
            const int sHi = s & 0x38;
            const int low = nl ^ (s & 3);
            const float4* base = wlds[r1];
            const float4* wrA = base + ((s & 4) | low);          // chunks c even
            const float4* wrB = base + (((s & 4) ^ 4) | low);    // chunks c odd
            float xf[8] = {xa1.x, xa1.y, xa1.z, xa1.w,
                           xb1.x, xb1.y, xb1.z, xb1.w};
            float a0 = 0.f, a1 = 0.f, a2 = 0.f, a3 = 0.f;
            float a4 = 0.f, a5 = 0.f, a6 = 0.f, a7 = 0.f;
            #pragma unroll
            for (int i = 0; i < 8; ++i) {        // ascending i: same order as r2-r5
                int off = (i << 3) ^ sHi;        // disjoint bit fields: + == |
                float4 wA = wrA[off];            // w[r][n][i][0..4)
                float4 wB = wrB[off];            // w[r][n][i][4..8)
                float xi = xf[i];
                a0 = fmaf(xi, wA.x, a0);
                a1 = fmaf(xi, wA.y, a1);
                a2 = fmaf(xi, wA.z, a2);
                a3 = fmaf(xi, wA.w, a3);
                a4 = fmaf(xi, wB.x, a4);
                a5 = fmaf(xi, wB.y, a5);
                a6 = fmaf(xi, wB.z, a6);
                a7 = fmaf(xi, wB.w, a7);
            }
            float4* ov = reinterpret_cast<float4*>(ob + (size_t)p1 * 128);
            ov[0] = make_float4(a0, a1, a2, a3);
            ov[1] = make_float4(a4, a5, a6, a7);
        }

        if (p2 >= phi) break;
        p1 = p2;  r1 = r2; xa1 = xa2; xb1 = xb2;
        p2 = p3;  r2 = r3; xa2 = xa3; xb2 = xb3;
    }
}

// ---------- fallback (round-2 kernel) for unexpected shapes ----------
__global__ __launch_bounds__(256) void brl_kernel(
    const float* __restrict__ x, const float* __restrict__ w,
    const int* __restrict__ rel, float* __restrict__ out, int npoints)
{
    int tid = blockIdx.x * 256 + threadIdx.x;
    int p = tid >> 4;
    if (p >= npoints) return;
    int n = tid & 15;
    int r = rel[p];
    const float4* xv = reinterpret_cast<const float4*>(x + (size_t)p * 128 + n * 8);
    float4 x0 = xv[0], x1 = xv[1];
    float xf[8] = {x0.x, x0.y, x0.z, x0.w, x1.x, x1.y, x1.z, x1.w};
    const float4* wv = reinterpret_cast<const float4*>(w + ((size_t)r * 16 + n) * 64);
    float acc[8] = {0.f, 0.f, 0.f, 0.f, 0.f, 0.f, 0.f, 0.f};
    #pragma unroll
    for (int i = 0; i < 8; ++i) {
        float4 w0 = wv[2 * i], w1 = wv[2 * i + 1];
        float wf[8] = {w0.x, w0.y, w0.z, w0.w, w1.x, w1.y, w1.z, w1.w};
        #pragma unroll
        for (int o = 0; o < 8; ++o) acc[o] = fmaf(xf[i], wf[o], acc[o]);
    }
    float4* ov = reinterpret_cast<float4*>(out + (size_t)p * 128 + n * 8);
    ov[0] = make_float4(acc[0], acc[1], acc[2], acc[3]);
    ov[1] = make_float4(acc[4], acc[5], acc[6], acc[7]);
}

extern "C" void kernel_launch(void* const* d_in, const int* in_sizes, int n_in,
                              void* d_out, int out_size, void* d_ws, size_t ws_size,
                              hipStream_t stream) {
    const float* x   = (const float*)d_in[0];
    const float* w   = (const float*)d_in[1];
    const int*   rel = (const int*)d_in[2];
    float*       out = (float*)d_out;

    int npoints = in_sizes[2];
    int R = in_sizes[1] / 1024;          // R * nb(16) * ib(8) * ob(8)

    if (R == 128 && in_sizes[0] == npoints * 128) {
        k_fused<<<256, 1024, 0, stream>>>(x, w, rel, out, npoints);
    } else {
        int total = npoints * 16;
        brl_kernel<<<(total + 255) / 256, 256, 0, stream>>>(x, w, rel, out, npoints);
    }
}